// Round 7
// baseline (358.336 us; speedup 1.0000x reference)
//
#include <hip/hip_runtime.h>
#include <stdint.h>

// HashEmbedder (Instant-NGP hash grid), MI355X gfx950.
// R6 -> R7: R6's 32 forced-live gather results (64 VGPRs) blew the RA's
// default ~64-reg budget -> scratch spills of in-flight loads = serializing
// waitcnts (VGPR=56 + spills, 243us). Rule: forced MLP must FIT the default
// budget. 2 pts/thread x 8 gathers = 16 live pairs (32 regs) + ~20 temps
// ~= 56 total, no launch_bounds. Staged GWAIT(8): pt0 interp overlaps pt1's
// 8 in-flight loads. Keeps XCD level-pinning (FETCH 54MB) + SoA ws (WRITE
// 65MB) + transpose kernel (~23us, near BW floor).

#define TABLE_SIZE (1u << 19)
#define TMASK (TABLE_SIZE - 1u)
#define P2 2654435761u
#define P3 805459861u

typedef __attribute__((ext_vector_type(2))) float f32x2;

// Issue one 8-byte gather; result forced into a live VGPR pair.
#define GLOAD(dst, ptr) \
    asm volatile("global_load_dwordx2 %0, %1, off" : "=v"(dst) : "v"(ptr));

// Wait until at most `cnt` VMEM ops outstanding; ties the 8 results consumed
// next so their uses cannot be hoisted above this wait.
#define GWAIT(cnt, a0,a1,a2,a3,a4,a5,a6,a7) \
    asm volatile("s_waitcnt vmcnt(" #cnt ")" \
        : "+v"(a0), "+v"(a1), "+v"(a2), "+v"(a3), \
          "+v"(a4), "+v"(a5), "+v"(a6), "+v"(a7));

// ---------------- kernel 1: per-(level, point) embed, SoA output ----------
// grid: blocks_per_level*8, level = blockIdx & 7 (round-robin -> XCD pinned)
// block: 256 threads x 2 points -> 512 points/block.
__global__ void hash_embed_soa_kernel(
    const float* __restrict__ x, const float* __restrict__ tables,
    f32x2* __restrict__ ws, int n)
{
    const uint32_t bid = blockIdx.x;
    const int l = (int)(bid & 7u);                  // level -> XCD pinned
    const int base = (int)(bid >> 3) * 512 + (int)threadIdx.x;
    if (base >= n) return;

    float R;
    switch (l) {
        case 0: R = 16.f; break;
        case 1: R = 20.f; break;
        case 2: R = 25.f; break;
        case 3: R = 32.f; break;
        case 4: R = 40.f; break;
        case 5: R = 50.f; break;
        case 6: R = 64.f; break;
        default: R = 80.f; break;
    }
    const float g = 1.0f / R;
    const f32x2* __restrict__ tab =
        (const f32x2*)(tables) + (size_t)l * (size_t)TABLE_SIZE;

    const int i0 = base, i1 = base + 256;

    const float px0 = x[3*i0+0], py0 = x[3*i0+1], pz0 = x[3*i0+2];
    const float px1 = x[3*i1+0], py1 = x[3*i1+1], pz1 = x[3*i1+2];

#define PREP(k) \
    const float cx##k = fminf(fmaxf(px##k, 0.0f), 1.0f); \
    const float cy##k = fminf(fmaxf(py##k, 0.0f), 1.0f); \
    const float cz##k = fminf(fmaxf(pz##k, 0.0f), 1.0f); \
    const int bx##k = (int)floorf(cx##k * R); \
    const int by##k = (int)floorf(cy##k * R); \
    const int bz##k = (int)floorf(cz##k * R); \
    const float wx##k = (px##k - (float)bx##k * g) * R; \
    const float wy##k = (py##k - (float)by##k * g) * R; \
    const float wz##k = (pz##k - (float)bz##k * g) * R; \
    const uint32_t hx0##k = (uint32_t)bx##k; \
    const uint32_t hx1##k = hx0##k + 1u; \
    const uint32_t hy0##k = (uint32_t)by##k * P2; \
    const uint32_t hy1##k = hy0##k + P2; \
    const uint32_t hz0##k = (uint32_t)bz##k * P3; \
    const uint32_t hz1##k = hz0##k + P3;

    PREP(0) PREP(1)

    f32x2 e00, e10, e20, e30, e40, e50, e60, e70;
    f32x2 e01, e11, e21, e31, e41, e51, e61, e71;

#define ISSUE(k) \
    GLOAD(e0##k, tab + ((hx0##k ^ hy0##k ^ hz0##k) & TMASK)) \
    GLOAD(e1##k, tab + ((hx0##k ^ hy0##k ^ hz1##k) & TMASK)) \
    GLOAD(e2##k, tab + ((hx0##k ^ hy1##k ^ hz0##k) & TMASK)) \
    GLOAD(e3##k, tab + ((hx0##k ^ hy1##k ^ hz1##k) & TMASK)) \
    GLOAD(e4##k, tab + ((hx1##k ^ hy0##k ^ hz0##k) & TMASK)) \
    GLOAD(e5##k, tab + ((hx1##k ^ hy0##k ^ hz1##k) & TMASK)) \
    GLOAD(e6##k, tab + ((hx1##k ^ hy1##k ^ hz0##k) & TMASK)) \
    GLOAD(e7##k, tab + ((hx1##k ^ hy1##k ^ hz1##k) & TMASK))

    // 16 gathers in flight
    ISSUE(0) ISSUE(1)

#define INTERP(k, dst) { \
    const float omx = 1.0f - wx##k, omy = 1.0f - wy##k, omz = 1.0f - wz##k; \
    const float c00a = e0##k.x * omx + e4##k.x * wx##k; \
    const float c00b = e0##k.y * omx + e4##k.y * wx##k; \
    const float c01a = e1##k.x * omx + e5##k.x * wx##k; \
    const float c01b = e1##k.y * omx + e5##k.y * wx##k; \
    const float c10a = e2##k.x * omx + e6##k.x * wx##k; \
    const float c10b = e2##k.y * omx + e6##k.y * wx##k; \
    const float c11a = e3##k.x * omx + e7##k.x * wx##k; \
    const float c11b = e3##k.y * omx + e7##k.y * wx##k; \
    const float c0a = c00a * omy + c10a * wy##k; \
    const float c0b = c00b * omy + c10b * wy##k; \
    const float c1a = c01a * omy + c11a * wy##k; \
    const float c1b = c01b * omy + c11b * wy##k; \
    dst.x = c0a * omz + c1a * wz##k; \
    dst.y = c0b * omz + c1b * wz##k; }

    f32x2 r0, r1;
    GWAIT(8, e00, e10, e20, e30, e40, e50, e60, e70)   // pt0 done, pt1 in flight
    INTERP(0, r0)
    GWAIT(0, e01, e11, e21, e31, e41, e51, e61, e71)
    INTERP(1, r1)

    f32x2* __restrict__ wl = ws + (size_t)l * (size_t)n;
    wl[i0] = r0;
    wl[i1] = r1;
}

// ---------------- kernel 2: SoA -> AoS transpose --------------------------
__global__ __launch_bounds__(256) void soa_to_aos_kernel(
    const f32x2* __restrict__ ws, float* __restrict__ out, int n)
{
    const int i = blockIdx.x * 256 + threadIdx.x;
    if (i >= n) return;

    const f32x2 v0 = ws[0 * (size_t)n + i];
    const f32x2 v1 = ws[1 * (size_t)n + i];
    const f32x2 v2 = ws[2 * (size_t)n + i];
    const f32x2 v3 = ws[3 * (size_t)n + i];
    const f32x2 v4 = ws[4 * (size_t)n + i];
    const f32x2 v5 = ws[5 * (size_t)n + i];
    const f32x2 v6 = ws[6 * (size_t)n + i];
    const f32x2 v7 = ws[7 * (size_t)n + i];

    float4* __restrict__ op = (float4*)(out + (size_t)i * 16);
    op[0] = make_float4(v0.x, v0.y, v1.x, v1.y);
    op[1] = make_float4(v2.x, v2.y, v3.x, v3.y);
    op[2] = make_float4(v4.x, v4.y, v5.x, v5.y);
    op[3] = make_float4(v6.x, v6.y, v7.x, v7.y);
}

// ---------------- fallback (ws too small): monolithic ---------------------
__global__ __launch_bounds__(256) void hash_embed_mono_kernel(
    const float* __restrict__ x, const float* __restrict__ tables,
    float* __restrict__ out, int n)
{
    const int i = blockIdx.x * 256 + threadIdx.x;
    if (i >= n) return;
    const float px = x[3*i+0], py = x[3*i+1], pz = x[3*i+2];
    const float cx = fminf(fmaxf(px, 0.0f), 1.0f);
    const float cy = fminf(fmaxf(py, 0.0f), 1.0f);
    const float cz = fminf(fmaxf(pz, 0.0f), 1.0f);
    const float resf[8] = {16.f,20.f,25.f,32.f,40.f,50.f,64.f,80.f};
    float o[16];
#pragma unroll
    for (int l = 0; l < 8; ++l) {
        const float R = resf[l], g = 1.0f / R;
        const int bx = (int)floorf(cx*R), by = (int)floorf(cy*R), bz = (int)floorf(cz*R);
        const float wx = (px - bx*g)*R, wy = (py - by*g)*R, wz = (pz - bz*g)*R;
        const uint32_t hx0 = (uint32_t)bx, hx1 = hx0+1u;
        const uint32_t hy0 = (uint32_t)by*P2, hy1 = hy0+P2;
        const uint32_t hz0 = (uint32_t)bz*P3, hz1 = hz0+P3;
        const float2* tab = (const float2*)(tables) + (size_t)l*(size_t)TABLE_SIZE;
        const float2 e000 = tab[(hx0^hy0^hz0)&TMASK], e001 = tab[(hx0^hy0^hz1)&TMASK];
        const float2 e010 = tab[(hx0^hy1^hz0)&TMASK], e011 = tab[(hx0^hy1^hz1)&TMASK];
        const float2 e100 = tab[(hx1^hy0^hz0)&TMASK], e101 = tab[(hx1^hy0^hz1)&TMASK];
        const float2 e110 = tab[(hx1^hy1^hz0)&TMASK], e111 = tab[(hx1^hy1^hz1)&TMASK];
        const float omx = 1.f-wx, omy = 1.f-wy, omz = 1.f-wz;
        const float c00a = e000.x*omx + e100.x*wx, c00b = e000.y*omx + e100.y*wx;
        const float c01a = e001.x*omx + e101.x*wx, c01b = e001.y*omx + e101.y*wx;
        const float c10a = e010.x*omx + e110.x*wx, c10b = e010.y*omx + e110.y*wx;
        const float c11a = e011.x*omx + e111.x*wx, c11b = e011.y*omx + e111.y*wx;
        const float c0a = c00a*omy + c10a*wy, c0b = c00b*omy + c10b*wy;
        const float c1a = c01a*omy + c11a*wy, c1b = c01b*omy + c11b*wy;
        o[2*l+0] = c0a*omz + c1a*wz;
        o[2*l+1] = c0b*omz + c1b*wz;
    }
    float4* op = (float4*)(out + (size_t)i * 16);
    op[0] = make_float4(o[0],o[1],o[2],o[3]);
    op[1] = make_float4(o[4],o[5],o[6],o[7]);
    op[2] = make_float4(o[8],o[9],o[10],o[11]);
    op[3] = make_float4(o[12],o[13],o[14],o[15]);
}

extern "C" void kernel_launch(void* const* d_in, const int* in_sizes, int n_in,
                              void* d_out, int out_size, void* d_ws, size_t ws_size,
                              hipStream_t stream) {
    const float* x = (const float*)d_in[0];
    const float* tables = (const float*)d_in[1];
    float* out = (float*)d_out;
    const int n = in_sizes[0] / 3;  // 1048576 points

    const size_t ws_needed = (size_t)8 * (size_t)n * sizeof(f32x2);  // 64 MB
    if (ws_size >= ws_needed && (n % 512) == 0) {
        f32x2* ws = (f32x2*)d_ws;
        const int blocks_per_level = n / 512;    // 512 points per block
        hash_embed_soa_kernel<<<blocks_per_level * 8, 256, 0, stream>>>(x, tables, ws, n);
        soa_to_aos_kernel<<<(n + 255) / 256, 256, 0, stream>>>(ws, out, n);
    } else {
        hash_embed_mono_kernel<<<(n + 255) / 256, 256, 0, stream>>>(x, tables, out, n);
    }
}

// Round 8
// 291.790 us; speedup vs baseline: 1.2281x; 1.2281x over previous
//
#include <hip/hip_runtime.h>
#include <stdint.h>

// HashEmbedder (Instant-NGP hash grid), MI355X gfx950.
// R7 -> R8: REVERT to the R4 configuration (best known: bench 297us,
// k1=182us k2=23us). Post-mortem of R5-R7: forcing >8-deep per-thread MLP
// via inline asm always triggers RA spills of in-flight loads (VGPR=56/28 <
// required live set) which serialize the gathers (243us). Cross-round data
// shows outstanding requests/CU saturates at ~150 regardless of structure
// (R1:163, R4:143) -> HW MSHR wall. k1 floor = 150 outst / ~250cyc L2 lat
// = 0.6 req/cyc = ~173us; R4's k1=182us is 95% of that. k2 runs at 89% of
// achievable HBM BW. This revert restores the known-best kernel unchanged.

#define TABLE_SIZE (1u << 19)
#define TMASK (TABLE_SIZE - 1u)
#define P2 2654435761u
#define P3 805459861u

// ---------------- kernel 1: per-(level, point) embed, SoA output ----------
// grid: blocks_per_level*8, level = blockIdx & 7 (round-robin -> XCD pinned)
// block handles 1024 points of one level: thread t -> points base+t+{0,256,512,768}

__global__ __launch_bounds__(256, 4) void hash_embed_soa_kernel(
    const float* __restrict__ x, const float* __restrict__ tables,
    float2* __restrict__ ws, int n)
{
    const uint32_t bid = blockIdx.x;
    const int l = (int)(bid & 7u);
    const int base = (int)(bid >> 3) * 1024 + (int)threadIdx.x;
    if (base >= n) return;

    float R;
    switch (l) {
        case 0: R = 16.f; break;
        case 1: R = 20.f; break;
        case 2: R = 25.f; break;
        case 3: R = 32.f; break;
        case 4: R = 40.f; break;
        case 5: R = 50.f; break;
        case 6: R = 64.f; break;
        default: R = 80.f; break;
    }
    const float g = 1.0f / R;
    const float2* __restrict__ tab =
        (const float2*)(tables) + (size_t)l * (size_t)TABLE_SIZE;

    const int i0 = base, i1 = base + 256, i2 = base + 512, i3 = base + 768;

    // ---- coords for 4 points ----
    const float px0 = x[3*i0+0], py0 = x[3*i0+1], pz0 = x[3*i0+2];
    const float px1 = x[3*i1+0], py1 = x[3*i1+1], pz1 = x[3*i1+2];
    const float px2 = x[3*i2+0], py2 = x[3*i2+1], pz2 = x[3*i2+2];
    const float px3 = x[3*i3+0], py3 = x[3*i3+1], pz3 = x[3*i3+2];

#define PREP(k) \
    const float cx##k = fminf(fmaxf(px##k, 0.0f), 1.0f); \
    const float cy##k = fminf(fmaxf(py##k, 0.0f), 1.0f); \
    const float cz##k = fminf(fmaxf(pz##k, 0.0f), 1.0f); \
    const int bx##k = (int)floorf(cx##k * R); \
    const int by##k = (int)floorf(cy##k * R); \
    const int bz##k = (int)floorf(cz##k * R); \
    const float wx##k = (px##k - (float)bx##k * g) * R; \
    const float wy##k = (py##k - (float)by##k * g) * R; \
    const float wz##k = (pz##k - (float)bz##k * g) * R; \
    const uint32_t hx0##k = (uint32_t)bx##k; \
    const uint32_t hx1##k = hx0##k + 1u; \
    const uint32_t hy0##k = (uint32_t)by##k * P2; \
    const uint32_t hy1##k = hy0##k + P2; \
    const uint32_t hz0##k = (uint32_t)bz##k * P3; \
    const uint32_t hz1##k = hz0##k + P3;

    PREP(0) PREP(1) PREP(2) PREP(3)

    // ---- 32 gathers, scalar named results (RA-friendly) ----
#define GATHER(k) \
    const float2 e0##k = tab[(hx0##k ^ hy0##k ^ hz0##k) & TMASK]; \
    const float2 e1##k = tab[(hx0##k ^ hy0##k ^ hz1##k) & TMASK]; \
    const float2 e2##k = tab[(hx0##k ^ hy1##k ^ hz0##k) & TMASK]; \
    const float2 e3##k = tab[(hx0##k ^ hy1##k ^ hz1##k) & TMASK]; \
    const float2 e4##k = tab[(hx1##k ^ hy0##k ^ hz0##k) & TMASK]; \
    const float2 e5##k = tab[(hx1##k ^ hy0##k ^ hz1##k) & TMASK]; \
    const float2 e6##k = tab[(hx1##k ^ hy1##k ^ hz0##k) & TMASK]; \
    const float2 e7##k = tab[(hx1##k ^ hy1##k ^ hz1##k) & TMASK];

    GATHER(0) GATHER(1) GATHER(2) GATHER(3)

#define INTERP(k, dst) { \
    const float omx = 1.0f - wx##k, omy = 1.0f - wy##k, omz = 1.0f - wz##k; \
    const float c00a = e0##k.x * omx + e4##k.x * wx##k; \
    const float c00b = e0##k.y * omx + e4##k.y * wx##k; \
    const float c01a = e1##k.x * omx + e5##k.x * wx##k; \
    const float c01b = e1##k.y * omx + e5##k.y * wx##k; \
    const float c10a = e2##k.x * omx + e6##k.x * wx##k; \
    const float c10b = e2##k.y * omx + e6##k.y * wx##k; \
    const float c11a = e3##k.x * omx + e7##k.x * wx##k; \
    const float c11b = e3##k.y * omx + e7##k.y * wx##k; \
    const float c0a = c00a * omy + c10a * wy##k; \
    const float c0b = c00b * omy + c10b * wy##k; \
    const float c1a = c01a * omy + c11a * wy##k; \
    const float c1b = c01b * omy + c11b * wy##k; \
    dst.x = c0a * omz + c1a * wz##k; \
    dst.y = c0b * omz + c1b * wz##k; }

    float2 r0, r1, r2, r3;
    INTERP(0, r0) INTERP(1, r1) INTERP(2, r2) INTERP(3, r3)

    // SoA store: per instruction, 64 lanes write 64 consecutive float2 = full lines
    float2* __restrict__ wl = ws + (size_t)l * (size_t)n;
    wl[i0] = r0;
    wl[i1] = r1;
    wl[i2] = r2;
    wl[i3] = r3;
}

// ---------------- kernel 2: SoA -> AoS transpose (register-only) ----------
__global__ __launch_bounds__(256) void soa_to_aos_kernel(
    const float2* __restrict__ ws, float* __restrict__ out, int n)
{
    const int i = blockIdx.x * 256 + threadIdx.x;
    if (i >= n) return;

    // 8 coalesced float2 loads (each: 64 lanes x consecutive 8 B)
    const float2 v0 = ws[0 * (size_t)n + i];
    const float2 v1 = ws[1 * (size_t)n + i];
    const float2 v2 = ws[2 * (size_t)n + i];
    const float2 v3 = ws[3 * (size_t)n + i];
    const float2 v4 = ws[4 * (size_t)n + i];
    const float2 v5 = ws[5 * (size_t)n + i];
    const float2 v6 = ws[6 * (size_t)n + i];
    const float2 v7 = ws[7 * (size_t)n + i];

    float4* __restrict__ op = (float4*)(out + (size_t)i * 16);
    op[0] = make_float4(v0.x, v0.y, v1.x, v1.y);
    op[1] = make_float4(v2.x, v2.y, v3.x, v3.y);
    op[2] = make_float4(v4.x, v4.y, v5.x, v5.y);
    op[3] = make_float4(v6.x, v6.y, v7.x, v7.y);
}

// ---------------- fallback (ws too small): monolithic ---------------------
__global__ __launch_bounds__(256) void hash_embed_mono_kernel(
    const float* __restrict__ x, const float* __restrict__ tables,
    float* __restrict__ out, int n)
{
    const int i = blockIdx.x * 256 + threadIdx.x;
    if (i >= n) return;
    const float px = x[3*i+0], py = x[3*i+1], pz = x[3*i+2];
    const float cx = fminf(fmaxf(px, 0.0f), 1.0f);
    const float cy = fminf(fmaxf(py, 0.0f), 1.0f);
    const float cz = fminf(fmaxf(pz, 0.0f), 1.0f);
    const float resf[8] = {16.f,20.f,25.f,32.f,40.f,50.f,64.f,80.f};
    float o[16];
#pragma unroll
    for (int l = 0; l < 8; ++l) {
        const float R = resf[l], g = 1.0f / R;
        const int bx = (int)floorf(cx*R), by = (int)floorf(cy*R), bz = (int)floorf(cz*R);
        const float wx = (px - bx*g)*R, wy = (py - by*g)*R, wz = (pz - bz*g)*R;
        const uint32_t hx0 = (uint32_t)bx, hx1 = hx0+1u;
        const uint32_t hy0 = (uint32_t)by*P2, hy1 = hy0+P2;
        const uint32_t hz0 = (uint32_t)bz*P3, hz1 = hz0+P3;
        const float2* tab = (const float2*)(tables) + (size_t)l*(size_t)TABLE_SIZE;
        const float2 e000 = tab[(hx0^hy0^hz0)&TMASK], e001 = tab[(hx0^hy0^hz1)&TMASK];
        const float2 e010 = tab[(hx0^hy1^hz0)&TMASK], e011 = tab[(hx0^hy1^hz1)&TMASK];
        const float2 e100 = tab[(hx1^hy0^hz0)&TMASK], e101 = tab[(hx1^hy0^hz1)&TMASK];
        const float2 e110 = tab[(hx1^hy1^hz0)&TMASK], e111 = tab[(hx1^hy1^hz1)&TMASK];
        const float omx = 1.f-wx, omy = 1.f-wy, omz = 1.f-wz;
        const float c00a = e000.x*omx + e100.x*wx, c00b = e000.y*omx + e100.y*wx;
        const float c01a = e001.x*omx + e101.x*wx, c01b = e001.y*omx + e101.y*wx;
        const float c10a = e010.x*omx + e110.x*wx, c10b = e010.y*omx + e110.y*wx;
        const float c11a = e011.x*omx + e111.x*wx, c11b = e011.y*omx + e111.y*wx;
        const float c0a = c00a*omy + c10a*wy, c0b = c00b*omy + c10b*wy;
        const float c1a = c01a*omy + c11a*wy, c1b = c01b*omy + c11b*wy;
        o[2*l+0] = c0a*omz + c1a*wz;
        o[2*l+1] = c0b*omz + c1b*wz;
    }
    float4* op = (float4*)(out + (size_t)i * 16);
    op[0] = make_float4(o[0],o[1],o[2],o[3]);
    op[1] = make_float4(o[4],o[5],o[6],o[7]);
    op[2] = make_float4(o[8],o[9],o[10],o[11]);
    op[3] = make_float4(o[12],o[13],o[14],o[15]);
}

extern "C" void kernel_launch(void* const* d_in, const int* in_sizes, int n_in,
                              void* d_out, int out_size, void* d_ws, size_t ws_size,
                              hipStream_t stream) {
    const float* x = (const float*)d_in[0];
    const float* tables = (const float*)d_in[1];
    float* out = (float*)d_out;
    const int n = in_sizes[0] / 3;  // 1048576 points

    const size_t ws_needed = (size_t)8 * (size_t)n * sizeof(float2);  // 64 MB
    if (ws_size >= ws_needed) {
        float2* ws = (float2*)d_ws;
        const int ppb = 1024;  // points per block in k1
        const int blocks_per_level = (n + ppb - 1) / ppb;
        hash_embed_soa_kernel<<<blocks_per_level * 8, 256, 0, stream>>>(x, tables, ws, n);
        soa_to_aos_kernel<<<(n + 255) / 256, 256, 0, stream>>>(ws, out, n);
    } else {
        hash_embed_mono_kernel<<<(n + 255) / 256, 256, 0, stream>>>(x, tables, out, n);
    }
}